// Round 1
// baseline (4991.771 us; speedup 1.0000x reference)
//
#include <hip/hip_runtime.h>
#include <hip/hip_bf16.h>
#include <math.h>

// SSMBlock: B=8, T=2048, C=1024, NF=64.  R = B*T = 16384 rows.
// Round 1: all-fp32 correctness baseline.
//   k1: qv = x@attn_W + attn_b   -> q (d_out), v (ws)
//   k2: 11x scan_step (fused f=z@W1, sincos, z2=s@W2, mmnorm), ping-pong d_out<->ws
//   k3: out = (q*v)@proj_W + proj_b
// ws layout: q_a [R*C f32] | v [R*C f32]  = 128 MiB total.

#define R_ROWS 16384
#define T_DIM  2048
#define C_DIM  1024

// ---------------------------------------------------------------- SGEMM: qv
// C[m,n] = sum_k X[m,k]*W[k,n] + b[n]; M=16384, K=1024, N=2048. BM=BN=64, BK=16.
__global__ __launch_bounds__(256) void gemm_qv_kernel(
    const float* __restrict__ X, const float* __restrict__ W,
    const float* __restrict__ bias, float* __restrict__ Q, float* __restrict__ V) {
  __shared__ float As[16][64];
  __shared__ float Bs[16][64];
  const int tid = threadIdx.x;
  const int m0 = blockIdx.x * 64;
  const int n0 = blockIdx.y * 64;
  const int tx = tid & 15, ty = tid >> 4;
  const int la_m = tid >> 2;          // 0..63
  const int la_k = (tid & 3) << 2;    // 0,4,8,12
  const int lb_k = tid >> 6;          // 0..3
  const int lb_n = tid & 63;
  float acc[4][4] = {};
  for (int k0 = 0; k0 < 1024; k0 += 16) {
    const float4 a4 = *(const float4*)&X[(size_t)(m0 + la_m) * 1024 + k0 + la_k];
    float bv[4];
#pragma unroll
    for (int i = 0; i < 4; i++)
      bv[i] = W[(size_t)(k0 + lb_k + 4 * i) * 2048 + n0 + lb_n];
    __syncthreads();
    As[la_k + 0][la_m] = a4.x;
    As[la_k + 1][la_m] = a4.y;
    As[la_k + 2][la_m] = a4.z;
    As[la_k + 3][la_m] = a4.w;
#pragma unroll
    for (int i = 0; i < 4; i++) Bs[lb_k + 4 * i][lb_n] = bv[i];
    __syncthreads();
#pragma unroll
    for (int kk = 0; kk < 16; kk++) {
      const float4 av4 = *(const float4*)&As[kk][ty << 2];
      const float4 bv4 = *(const float4*)&Bs[kk][tx << 2];
      float a_[4] = {av4.x, av4.y, av4.z, av4.w};
      float b_[4] = {bv4.x, bv4.y, bv4.z, bv4.w};
#pragma unroll
      for (int i = 0; i < 4; i++)
#pragma unroll
        for (int j = 0; j < 4; j++) acc[i][j] += a_[i] * b_[j];
    }
  }
  const int nb = n0 + (tx << 2);
  const float4 b4 = *(const float4*)&bias[nb];
  const float bb_[4] = {b4.x, b4.y, b4.z, b4.w};
#pragma unroll
  for (int i = 0; i < 4; i++) {
    const int m = m0 + (ty << 2) + i;
    float4 o;
    o.x = acc[i][0] + bb_[0];
    o.y = acc[i][1] + bb_[1];
    o.z = acc[i][2] + bb_[2];
    o.w = acc[i][3] + bb_[3];
    if (nb < 1024) *(float4*)&Q[(size_t)m * 1024 + nb] = o;
    else           *(float4*)&V[(size_t)m * 1024 + nb - 1024] = o;
  }
}

// ---------------------------------------------------------------- SGEMM: proj
// out[m,n] = sum_k (QF[m,k]*VV[m,k])*W[k,n] + b[n]; M=16384, K=1024, N=1024.
__global__ __launch_bounds__(256) void gemm_proj_kernel(
    const float* __restrict__ QF, const float* __restrict__ VV,
    const float* __restrict__ W, const float* __restrict__ bias,
    float* __restrict__ OUT) {
  __shared__ float As[16][64];
  __shared__ float Bs[16][64];
  const int tid = threadIdx.x;
  const int m0 = blockIdx.x * 64;
  const int n0 = blockIdx.y * 64;
  const int tx = tid & 15, ty = tid >> 4;
  const int la_m = tid >> 2;
  const int la_k = (tid & 3) << 2;
  const int lb_k = tid >> 6;
  const int lb_n = tid & 63;
  float acc[4][4] = {};
  for (int k0 = 0; k0 < 1024; k0 += 16) {
    const size_t aoff = (size_t)(m0 + la_m) * 1024 + k0 + la_k;
    const float4 qa = *(const float4*)&QF[aoff];
    const float4 va = *(const float4*)&VV[aoff];
    float4 a4;
    a4.x = qa.x * va.x; a4.y = qa.y * va.y; a4.z = qa.z * va.z; a4.w = qa.w * va.w;
    float bv[4];
#pragma unroll
    for (int i = 0; i < 4; i++)
      bv[i] = W[(size_t)(k0 + lb_k + 4 * i) * 1024 + n0 + lb_n];
    __syncthreads();
    As[la_k + 0][la_m] = a4.x;
    As[la_k + 1][la_m] = a4.y;
    As[la_k + 2][la_m] = a4.z;
    As[la_k + 3][la_m] = a4.w;
#pragma unroll
    for (int i = 0; i < 4; i++) Bs[lb_k + 4 * i][lb_n] = bv[i];
    __syncthreads();
#pragma unroll
    for (int kk = 0; kk < 16; kk++) {
      const float4 av4 = *(const float4*)&As[kk][ty << 2];
      const float4 bv4 = *(const float4*)&Bs[kk][tx << 2];
      float a_[4] = {av4.x, av4.y, av4.z, av4.w};
      float b_[4] = {bv4.x, bv4.y, bv4.z, bv4.w};
#pragma unroll
      for (int i = 0; i < 4; i++)
#pragma unroll
        for (int j = 0; j < 4; j++) acc[i][j] += a_[i] * b_[j];
    }
  }
  const int nb = n0 + (tx << 2);
  const float4 b4 = *(const float4*)&bias[nb];
  const float bb_[4] = {b4.x, b4.y, b4.z, b4.w};
#pragma unroll
  for (int i = 0; i < 4; i++) {
    const int m = m0 + (ty << 2) + i;
    float4 o;
    o.x = acc[i][0] + bb_[0];
    o.y = acc[i][1] + bb_[1];
    o.z = acc[i][2] + bb_[2];
    o.w = acc[i][3] + bb_[3];
    *(float4*)&OUT[(size_t)m * 1024 + nb] = o;
  }
}

// ---------------------------------------------------------------- scan step
// Per block: 32 rows. z[r] = concat(y[r], x[r]) with y = (tl>=n) ? src[gr-n] : identity.
// Phase 1: f[32][64] = z @ W1 + b1  (W1 streamed from L2, Zs k-tiles in LDS)
// sincos -> St[32][128] in LDS
// Phase 2 (2 halves of 16 rows): z2[16][1024] = St @ W2 + b2; mmnorm; store dst.
__global__ __launch_bounds__(256) void scan_step_kernel(
    const float* __restrict__ src, float* __restrict__ dst,
    const float* __restrict__ W1, const float* __restrict__ b1,
    const float* __restrict__ W2, const float* __restrict__ b2,
    const float* __restrict__ ident, int n) {
  __shared__ float Zs[32][68];     // k-tile of z, padded
  __shared__ float St[32][132];    // sincos, padded
  __shared__ unsigned rmaxu[16];
  const int tid = threadIdx.x;
  const int r0 = blockIdx.x * 32;
  const int j = tid & 63;          // f column
  const int rgrp = tid >> 6;       // 0..3 -> rows rgrp*8..+7
  const int zr = tid >> 3;         // 0..31 z-load row
  const int zk = (tid & 7) << 3;   // 0..56 z-load col base (8 floats)
  const int gr_z = r0 + zr;
  const int tl_z = gr_z & (T_DIM - 1);

  float facc[8] = {0.f, 0.f, 0.f, 0.f, 0.f, 0.f, 0.f, 0.f};
  for (int kt = 0; kt < 2048; kt += 64) {
    float4 za, zb;
    if (kt < 1024) {  // y part
      const int k = kt + zk;
      if (tl_z >= n) {
        const float* p = &src[(size_t)(gr_z - n) * 1024 + k];
        za = *(const float4*)p;
        zb = *(const float4*)(p + 4);
      } else {
        za = *(const float4*)&ident[k];
        zb = *(const float4*)&ident[k + 4];
      }
    } else {          // x part
      const float* p = &src[(size_t)gr_z * 1024 + (kt - 1024) + zk];
      za = *(const float4*)p;
      zb = *(const float4*)(p + 4);
    }
    __syncthreads();
    *(float4*)&Zs[zr][zk] = za;
    *(float4*)&Zs[zr][zk + 4] = zb;
    __syncthreads();
#pragma unroll 4
    for (int kk = 0; kk < 64; kk += 4) {
      const int kg = kt + kk;
      const float w0 = W1[(size_t)(kg + 0) * 64 + j];
      const float w1 = W1[(size_t)(kg + 1) * 64 + j];
      const float w2 = W1[(size_t)(kg + 2) * 64 + j];
      const float w3 = W1[(size_t)(kg + 3) * 64 + j];
#pragma unroll
      for (int rr = 0; rr < 8; rr++) {
        const float4 z4 = *(const float4*)&Zs[(rgrp << 3) + rr][kk];
        facc[rr] += z4.x * w0 + z4.y * w1 + z4.z * w2 + z4.w * w3;
      }
    }
  }
  const float b1j = b1[j];
  __syncthreads();
#pragma unroll
  for (int rr = 0; rr < 8; rr++) {
    const float f = facc[rr] + b1j;
    float sv, cv;
    sincosf(f, &sv, &cv);
    const int r = (rgrp << 3) + rr;
    St[r][j] = sv;
    St[r][64 + j] = cv;
  }
  __syncthreads();

  const int c0 = tid << 2;  // 0..1020
  const float4 bb = *(const float4*)&b2[c0];
  for (int h = 0; h < 2; h++) {
    if (tid < 16) rmaxu[tid] = 0u;
    float4 acc[16];
#pragma unroll
    for (int rr = 0; rr < 16; rr++) acc[rr] = make_float4(0.f, 0.f, 0.f, 0.f);
#pragma unroll 2
    for (int i = 0; i < 128; i++) {
      const float4 w4 = *(const float4*)&W2[(size_t)i * 1024 + c0];
#pragma unroll
      for (int rr = 0; rr < 16; rr++) {
        const float s = St[(h << 4) + rr][i];
        acc[rr].x += s * w4.x;
        acc[rr].y += s * w4.y;
        acc[rr].z += s * w4.z;
        acc[rr].w += s * w4.w;
      }
    }
    __syncthreads();  // rmaxu init visible before atomics
#pragma unroll
    for (int rr = 0; rr < 16; rr++) {
      acc[rr].x += bb.x; acc[rr].y += bb.y; acc[rr].z += bb.z; acc[rr].w += bb.w;
      float m = fmaxf(fmaxf(fabsf(acc[rr].x), fabsf(acc[rr].y)),
                      fmaxf(fabsf(acc[rr].z), fabsf(acc[rr].w)));
#pragma unroll
      for (int off = 32; off > 0; off >>= 1)
        m = fmaxf(m, __shfl_xor(m, off, 64));
      if ((tid & 63) == 0) atomicMax(&rmaxu[rr], __float_as_uint(m));
    }
    __syncthreads();
#pragma unroll
    for (int rr = 0; rr < 16; rr++) {
      const float s = 1.0f / (__uint_as_float(rmaxu[rr]) + 1e-6f);
      float4 o;
      o.x = acc[rr].x * s; o.y = acc[rr].y * s;
      o.z = acc[rr].z * s; o.w = acc[rr].w * s;
      *(float4*)&dst[(size_t)(r0 + (h << 4) + rr) * 1024 + c0] = o;
    }
    __syncthreads();
  }
}

// ---------------------------------------------------------------- launch
extern "C" void kernel_launch(void* const* d_in, const int* in_sizes, int n_in,
                              void* d_out, int out_size, void* d_ws, size_t ws_size,
                              hipStream_t stream) {
  const float* x      = (const float*)d_in[0];
  const float* attn_W = (const float*)d_in[1];
  const float* attn_b = (const float*)d_in[2];
  const float* freq_W = (const float*)d_in[3];
  const float* freq_b = (const float*)d_in[4];
  const float* out_W  = (const float*)d_in[5];
  const float* out_b  = (const float*)d_in[6];
  const float* proj_W = (const float*)d_in[7];
  const float* proj_b = (const float*)d_in[8];
  const float* ident  = (const float*)d_in[9];
  float* out = (float*)d_out;

  float* q_a = (float*)d_ws;                       // R*C f32
  float* v   = q_a + (size_t)R_ROWS * C_DIM;       // R*C f32

  // k1: q -> d_out (used as scan buffer), v -> ws
  dim3 g1(R_ROWS / 64, 2048 / 64);
  gemm_qv_kernel<<<g1, 256, 0, stream>>>(x, attn_W, attn_b, out, v);

  // 11 scan steps, ping-pong d_out <-> q_a; odd count => final q in q_a
  float* qs = out;
  float* qd = q_a;
  for (int n = 1; n < T_DIM; n <<= 1) {
    scan_step_kernel<<<R_ROWS / 32, 256, 0, stream>>>(
        qs, qd, freq_W, freq_b, out_W, out_b, ident, n);
    float* t = qs; qs = qd; qd = t;
  }

  // k3: out = (q*v)@proj_W + proj_b   (qs == q_a, no alias with d_out)
  dim3 g3(R_ROWS / 64, 1024 / 64);
  gemm_proj_kernel<<<g3, 256, 0, stream>>>(qs, v, proj_W, proj_b, out);
}

// Round 2
// 2287.732 us; speedup vs baseline: 2.1820x; 2.1820x over previous
//
#include <hip/hip_runtime.h>
#include <hip/hip_bf16.h>
#include <math.h>

// SSMBlock: B=8, T=2048, C=1024, NF=64.  R = B*T = 16384 rows.
// Round 2: bf16 MFMA everywhere.
//   pre: transpose+cvt weights to bf16 [N][K] rows (K-contiguous for MFMA frags)
//        freq_W additionally split into hi/lo bf16 for near-fp32 phase-1.
//   k1: qv MFMA (128x128 tile) -> q fp32 (d_out), v bf16 (ws)
//   k2: 11x scan_mfma: phase1 f=z@W1 (split-bf16 MFMA), sincos, phase2 S@W2
//       (bf16 MFMA, B-frags straight from L2), fused mmnorm. ping-pong.
//   k3: proj MFMA with fused A=(q*v)->bf16 staging.
// ws: q_a f32 64MB | v_bf 32MB | aWt 4MB | pWt 2MB | w1h/w1l/w2t 0.75MB = ~103MB

#define R_ROWS 16384
#define T_DIM  2048
#define C_DIM  1024

typedef unsigned short u16;
typedef __attribute__((ext_vector_type(8))) short short8;
typedef __attribute__((ext_vector_type(4))) float f32x4;

__device__ __forceinline__ u16 f2bf(float f) {
  union { float f; unsigned u; } v; v.f = f;
  unsigned r = v.u + 0x7fffu + ((v.u >> 16) & 1u);
  return (u16)(r >> 16);
}
__device__ __forceinline__ float bf2f(u16 h) {
  union { unsigned u; float f; } v; v.u = ((unsigned)h) << 16;
  return v.f;
}

// ------------------------------------------------ weight transpose/convert
// Wt[n][k] = bf16(W[k][n]); K,N multiples of 32. block 256 = 32x8.
__global__ __launch_bounds__(256) void cvt_T(const float* __restrict__ W,
                                             u16* __restrict__ Wt, int K, int N) {
  __shared__ float t[32][33];
  const int k0 = blockIdx.x * 32, n0 = blockIdx.y * 32;
  const int tx = threadIdx.x & 31, ty = threadIdx.x >> 5;
#pragma unroll
  for (int i = 0; i < 32; i += 8)
    t[ty + i][tx] = W[(size_t)(k0 + ty + i) * N + n0 + tx];
  __syncthreads();
#pragma unroll
  for (int i = 0; i < 32; i += 8)
    Wt[(size_t)(n0 + ty + i) * K + k0 + tx] = f2bf(t[tx][ty + i]);
}

__global__ __launch_bounds__(256) void cvt_T_split(const float* __restrict__ W,
                                                   u16* __restrict__ Hi,
                                                   u16* __restrict__ Lo, int K, int N) {
  __shared__ float t[32][33];
  const int k0 = blockIdx.x * 32, n0 = blockIdx.y * 32;
  const int tx = threadIdx.x & 31, ty = threadIdx.x >> 5;
#pragma unroll
  for (int i = 0; i < 32; i += 8)
    t[ty + i][tx] = W[(size_t)(k0 + ty + i) * N + n0 + tx];
  __syncthreads();
#pragma unroll
  for (int i = 0; i < 32; i += 8) {
    const float x = t[tx][ty + i];
    const u16 h = f2bf(x);
    Hi[(size_t)(n0 + ty + i) * K + k0 + tx] = h;
    Lo[(size_t)(n0 + ty + i) * K + k0 + tx] = f2bf(x - bf2f(h));
  }
}

// ------------------------------------------------ qv GEMM (bf16 MFMA)
// C[m,n] = X[m,:]@W[:,n] + b; M=16384 K=1024 N=2048. Wt = [N][K] bf16.
// 128x128 tile, BK=64, 4 waves (2x2), 64x64 per wave, 16x16x32 MFMA.
__global__ __launch_bounds__(256) void gemm_qv_mfma(
    const float* __restrict__ X, const u16* __restrict__ Wt,
    const float* __restrict__ bias, float* __restrict__ Q, u16* __restrict__ Vb) {
  __shared__ u16 As[128 * 64];
  __shared__ u16 Bs[128 * 64];
  const int tid = threadIdx.x;
  const int lane = tid & 63, w = tid >> 6;
  const int ln = lane & 15, qd = lane >> 4;
  const int wm = w & 1, wn = w >> 1;
  const int m0 = blockIdx.x * 128, n0 = blockIdx.y * 128;
  const int sr = tid >> 1;            // staging row 0..127
  const int sc = (tid & 1) * 32;      // staging k-seg
  f32x4 acc[4][4] = {};
  for (int kt = 0; kt < 1024; kt += 64) {
    const float* xp = &X[(size_t)(m0 + sr) * 1024 + kt + sc];
    float4 xa[8];
#pragma unroll
    for (int i = 0; i < 8; i++) xa[i] = ((const float4*)xp)[i];
    const uint4* bp = (const uint4*)&Wt[(size_t)(n0 + sr) * 1024 + kt + sc];
    uint4 bb[4];
#pragma unroll
    for (int i = 0; i < 4; i++) bb[i] = bp[i];
    __syncthreads();
    alignas(16) u16 tmp[32];
#pragma unroll
    for (int i = 0; i < 8; i++) {
      tmp[4 * i + 0] = f2bf(xa[i].x); tmp[4 * i + 1] = f2bf(xa[i].y);
      tmp[4 * i + 2] = f2bf(xa[i].z); tmp[4 * i + 3] = f2bf(xa[i].w);
    }
#pragma unroll
    for (int i = 0; i < 4; i++) ((uint4*)&As[sr * 64 + sc])[i] = ((const uint4*)tmp)[i];
#pragma unroll
    for (int i = 0; i < 4; i++) ((uint4*)&Bs[sr * 64 + sc])[i] = bb[i];
    __syncthreads();
#pragma unroll
    for (int ks = 0; ks < 2; ks++) {
      short8 af[4], bf_[4];
#pragma unroll
      for (int i = 0; i < 4; i++)
        af[i] = *(const short8*)&As[(wm * 64 + i * 16 + ln) * 64 + ks * 32 + qd * 8];
#pragma unroll
      for (int j = 0; j < 4; j++)
        bf_[j] = *(const short8*)&Bs[(wn * 64 + j * 16 + ln) * 64 + ks * 32 + qd * 8];
#pragma unroll
      for (int i = 0; i < 4; i++)
#pragma unroll
        for (int j = 0; j < 4; j++)
          acc[i][j] = __builtin_amdgcn_mfma_f32_16x16x32_bf16(af[i], bf_[j], acc[i][j], 0, 0, 0);
    }
  }
  const bool isQ = (n0 < 1024);
#pragma unroll
  for (int i = 0; i < 4; i++) {
    const int rg = m0 + wm * 64 + i * 16 + qd * 4;
#pragma unroll
    for (int j = 0; j < 4; j++) {
      const int cg = n0 + wn * 64 + j * 16 + ln;
      const float bv = bias[cg];
#pragma unroll
      for (int r = 0; r < 4; r++) {
        const float vv = acc[i][j][r] + bv;
        if (isQ) Q[(size_t)(rg + r) * 1024 + cg] = vv;
        else     Vb[(size_t)(rg + r) * 1024 + (cg - 1024)] = f2bf(vv);
      }
    }
  }
}

// ------------------------------------------------ proj GEMM (bf16 MFMA)
// out[m,n] = (q[m,:]*v[m,:])@W[:,n] + b; M=16384 K=1024 N=1024. pWt=[N][K] bf16.
__global__ __launch_bounds__(256) void gemm_proj_mfma(
    const float* __restrict__ QF, const u16* __restrict__ Vb,
    const u16* __restrict__ Wt, const float* __restrict__ bias,
    float* __restrict__ OUT) {
  __shared__ u16 As[128 * 64];
  __shared__ u16 Bs[128 * 64];
  const int tid = threadIdx.x;
  const int lane = tid & 63, w = tid >> 6;
  const int ln = lane & 15, qd = lane >> 4;
  const int wm = w & 1, wn = w >> 1;
  const int m0 = blockIdx.x * 128, n0 = blockIdx.y * 128;
  const int sr = tid >> 1;
  const int sc = (tid & 1) * 32;
  f32x4 acc[4][4] = {};
  for (int kt = 0; kt < 1024; kt += 64) {
    const float* qp = &QF[(size_t)(m0 + sr) * 1024 + kt + sc];
    float4 qa[8];
#pragma unroll
    for (int i = 0; i < 8; i++) qa[i] = ((const float4*)qp)[i];
    alignas(16) uint4 vv[4];
    const uint4* vp = (const uint4*)&Vb[(size_t)(m0 + sr) * 1024 + kt + sc];
#pragma unroll
    for (int i = 0; i < 4; i++) vv[i] = vp[i];
    const uint4* bp = (const uint4*)&Wt[(size_t)(n0 + sr) * 1024 + kt + sc];
    uint4 bb[4];
#pragma unroll
    for (int i = 0; i < 4; i++) bb[i] = bp[i];
    __syncthreads();
    alignas(16) u16 tmp[32];
    const u16* vs = (const u16*)vv;
#pragma unroll
    for (int i = 0; i < 8; i++) {
      tmp[4 * i + 0] = f2bf(qa[i].x * bf2f(vs[4 * i + 0]));
      tmp[4 * i + 1] = f2bf(qa[i].y * bf2f(vs[4 * i + 1]));
      tmp[4 * i + 2] = f2bf(qa[i].z * bf2f(vs[4 * i + 2]));
      tmp[4 * i + 3] = f2bf(qa[i].w * bf2f(vs[4 * i + 3]));
    }
#pragma unroll
    for (int i = 0; i < 4; i++) ((uint4*)&As[sr * 64 + sc])[i] = ((const uint4*)tmp)[i];
#pragma unroll
    for (int i = 0; i < 4; i++) ((uint4*)&Bs[sr * 64 + sc])[i] = bb[i];
    __syncthreads();
#pragma unroll
    for (int ks = 0; ks < 2; ks++) {
      short8 af[4], bf_[4];
#pragma unroll
      for (int i = 0; i < 4; i++)
        af[i] = *(const short8*)&As[(wm * 64 + i * 16 + ln) * 64 + ks * 32 + qd * 8];
#pragma unroll
      for (int j = 0; j < 4; j++)
        bf_[j] = *(const short8*)&Bs[(wn * 64 + j * 16 + ln) * 64 + ks * 32 + qd * 8];
#pragma unroll
      for (int i = 0; i < 4; i++)
#pragma unroll
        for (int j = 0; j < 4; j++)
          acc[i][j] = __builtin_amdgcn_mfma_f32_16x16x32_bf16(af[i], bf_[j], acc[i][j], 0, 0, 0);
    }
  }
#pragma unroll
  for (int i = 0; i < 4; i++) {
    const int rg = m0 + wm * 64 + i * 16 + qd * 4;
#pragma unroll
    for (int j = 0; j < 4; j++) {
      const int cg = n0 + wn * 64 + j * 16 + ln;
      const float bv = bias[cg];
#pragma unroll
      for (int r = 0; r < 4; r++)
        OUT[(size_t)(rg + r) * 1024 + cg] = acc[i][j][r] + bv;
    }
  }
}

// ------------------------------------------------ scan step (MFMA)
// 32 rows/block. Phase1: f[32][64] = z[32][2048]@W1, split-bf16 (3 MFMA terms).
// sincos -> St[32][128] bf16 LDS. Phase2: z2[32][1024] = St@W2 (bf16 MFMA,
// B-frags from L2-resident W2t), + b2, row mmnorm, store fp32.
__global__ __launch_bounds__(256) void scan_mfma(
    const float* __restrict__ src, float* __restrict__ dst,
    const u16* __restrict__ W1h, const u16* __restrict__ W1l,
    const float* __restrict__ b1,
    const u16* __restrict__ W2t, const float* __restrict__ b2,
    const float* __restrict__ ident, int n) {
  __shared__ u16 Zh[32 * 256];
  __shared__ u16 Zl[32 * 256];
  __shared__ u16 St[32 * 128];
  __shared__ unsigned rmax[32];
  const int tid = threadIdx.x;
  const int lane = tid & 63, w = tid >> 6;
  const int ln = lane & 15, qd = lane >> 4;
  const int r0 = blockIdx.x * 32;
  // phase-1 tile assignment: wave w -> m-tile (w&1), n-tiles {w>>1, (w>>1)+2}
  const int mt = w & 1;
  const int nb = w >> 1;
  f32x4 fa[2] = {};
  // z staging assignment
  const int zr = tid >> 3;             // 0..31
  const int zs = (tid & 7) * 32;       // 0..224
  const int gr = r0 + zr;
  const int tl = gr & (T_DIM - 1);
  const float* ysrc = (tl >= n) ? &src[(size_t)(gr - n) * 1024] : ident;
  const float* xsrc = &src[(size_t)gr * 1024];

  for (int kc = 0; kc < 2048; kc += 256) {
    const int kk = kc + zs;
    const float* p = (kk < 1024) ? (ysrc + kk) : (xsrc + (kk - 1024));
    float4 zv[8];
#pragma unroll
    for (int i = 0; i < 8; i++) zv[i] = ((const float4*)p)[i];
    __syncthreads();
    alignas(16) u16 th[32], tlo[32];
#pragma unroll
    for (int i = 0; i < 8; i++) {
      const float xs[4] = {zv[i].x, zv[i].y, zv[i].z, zv[i].w};
#pragma unroll
      for (int c = 0; c < 4; c++) {
        const u16 h = f2bf(xs[c]);
        th[4 * i + c] = h;
        tlo[4 * i + c] = f2bf(xs[c] - bf2f(h));
      }
    }
#pragma unroll
    for (int i = 0; i < 4; i++) {
      ((uint4*)&Zh[zr * 256 + zs])[i] = ((const uint4*)th)[i];
      ((uint4*)&Zl[zr * 256 + zs])[i] = ((const uint4*)tlo)[i];
    }
    __syncthreads();
#pragma unroll
    for (int ks = 0; ks < 8; ks++) {
      const int ko = ks * 32 + qd * 8;
      const short8 ah = *(const short8*)&Zh[(mt * 16 + ln) * 256 + ko];
      const short8 al = *(const short8*)&Zl[(mt * 16 + ln) * 256 + ko];
#pragma unroll
      for (int t2 = 0; t2 < 2; t2++) {
        const int cn = (nb + 2 * t2) * 16 + ln;
        const short8 bh = *(const short8*)&W1h[(size_t)cn * 2048 + kc + ko];
        const short8 bl = *(const short8*)&W1l[(size_t)cn * 2048 + kc + ko];
        fa[t2] = __builtin_amdgcn_mfma_f32_16x16x32_bf16(ah, bh, fa[t2], 0, 0, 0);
        fa[t2] = __builtin_amdgcn_mfma_f32_16x16x32_bf16(al, bh, fa[t2], 0, 0, 0);
        fa[t2] = __builtin_amdgcn_mfma_f32_16x16x32_bf16(ah, bl, fa[t2], 0, 0, 0);
      }
    }
  }
  // sincos -> St (C-frag layout: row = quad*4+r, col = lane&15 within tile)
  if (tid < 32) rmax[tid] = 0u;
#pragma unroll
  for (int t2 = 0; t2 < 2; t2++) {
    const int cn = (nb + 2 * t2) * 16 + ln;
    const float b1v = b1[cn];
#pragma unroll
    for (int r = 0; r < 4; r++) {
      const float f = fa[t2][r] + b1v;
      float sv, cv;
      __sincosf(f, &sv, &cv);
      const int row = mt * 16 + qd * 4 + r;
      St[row * 128 + cn] = f2bf(sv);
      St[row * 128 + 64 + cn] = f2bf(cv);
    }
  }
  __syncthreads();
  // phase 2: wave w covers cols [w*256, w*256+256)
  f32x4 a2[2][16] = {};
#pragma unroll
  for (int ks = 0; ks < 4; ks++) {
    const int ko = ks * 32 + qd * 8;
    const short8 a0 = *(const short8*)&St[ln * 128 + ko];
    const short8 a1 = *(const short8*)&St[(16 + ln) * 128 + ko];
#pragma unroll
    for (int nt = 0; nt < 16; nt++) {
      const int cn = w * 256 + nt * 16 + ln;
      const short8 b = *(const short8*)&W2t[(size_t)cn * 128 + ko];
      a2[0][nt] = __builtin_amdgcn_mfma_f32_16x16x32_bf16(a0, b, a2[0][nt], 0, 0, 0);
      a2[1][nt] = __builtin_amdgcn_mfma_f32_16x16x32_bf16(a1, b, a2[1][nt], 0, 0, 0);
    }
  }
  // bias + per-row absmax
  float mx[2][4] = {{0.f, 0.f, 0.f, 0.f}, {0.f, 0.f, 0.f, 0.f}};
#pragma unroll
  for (int nt = 0; nt < 16; nt++) {
    const int cn = w * 256 + nt * 16 + ln;
    const float bv = b2[cn];
#pragma unroll
    for (int m = 0; m < 2; m++)
#pragma unroll
      for (int r = 0; r < 4; r++) {
        const float v = a2[m][nt][r] + bv;
        a2[m][nt][r] = v;
        mx[m][r] = fmaxf(mx[m][r], fabsf(v));
      }
  }
#pragma unroll
  for (int m = 0; m < 2; m++)
#pragma unroll
    for (int r = 0; r < 4; r++) {
      float v = mx[m][r];
      v = fmaxf(v, __shfl_xor(v, 1, 64));
      v = fmaxf(v, __shfl_xor(v, 2, 64));
      v = fmaxf(v, __shfl_xor(v, 4, 64));
      v = fmaxf(v, __shfl_xor(v, 8, 64));
      if (ln == 0) atomicMax(&rmax[m * 16 + qd * 4 + r], __float_as_uint(v));
    }
  __syncthreads();
#pragma unroll
  for (int m = 0; m < 2; m++)
#pragma unroll
    for (int r = 0; r < 4; r++) {
      const int row = m * 16 + qd * 4 + r;
      const float inv = 1.0f / (__uint_as_float(rmax[row]) + 1e-6f);
#pragma unroll
      for (int nt = 0; nt < 16; nt++) {
        const int cn = w * 256 + nt * 16 + ln;
        dst[(size_t)(r0 + row) * 1024 + cn] = a2[m][nt][r] * inv;
      }
    }
}

// ------------------------------------------------ launch
extern "C" void kernel_launch(void* const* d_in, const int* in_sizes, int n_in,
                              void* d_out, int out_size, void* d_ws, size_t ws_size,
                              hipStream_t stream) {
  const float* x      = (const float*)d_in[0];
  const float* attn_W = (const float*)d_in[1];
  const float* attn_b = (const float*)d_in[2];
  const float* freq_W = (const float*)d_in[3];
  const float* freq_b = (const float*)d_in[4];
  const float* out_W  = (const float*)d_in[5];
  const float* out_b  = (const float*)d_in[6];
  const float* proj_W = (const float*)d_in[7];
  const float* proj_b = (const float*)d_in[8];
  const float* ident  = (const float*)d_in[9];
  float* out = (float*)d_out;

  float* q_a = (float*)d_ws;                              // 16384*1024 f32
  u16*  v_bf = (u16*)(q_a + (size_t)R_ROWS * C_DIM);      // 16384*1024 bf16
  u16*  aWt  = v_bf + (size_t)R_ROWS * C_DIM;             // 2048*1024
  u16*  pWt  = aWt + (size_t)2048 * 1024;                 // 1024*1024
  u16*  w1h  = pWt + (size_t)1024 * 1024;                 // 64*2048
  u16*  w1l  = w1h + (size_t)64 * 2048;                   // 64*2048
  u16*  w2t  = w1l + (size_t)64 * 2048;                   // 1024*128

  // weight prep
  cvt_T<<<dim3(32, 64), 256, 0, stream>>>(attn_W, aWt, 1024, 2048);
  cvt_T<<<dim3(32, 32), 256, 0, stream>>>(proj_W, pWt, 1024, 1024);
  cvt_T<<<dim3(4, 32), 256, 0, stream>>>(out_W, w2t, 128, 1024);
  cvt_T_split<<<dim3(64, 2), 256, 0, stream>>>(freq_W, w1h, w1l, 2048, 64);

  // k1: q -> d_out fp32, v -> ws bf16
  gemm_qv_mfma<<<dim3(128, 16), 256, 0, stream>>>(x, aWt, attn_b, out, v_bf);

  // 11 scan steps, ping-pong d_out <-> q_a (odd count => final q in q_a)
  float* qs = out;
  float* qd = q_a;
  for (int n = 1; n < T_DIM; n <<= 1) {
    scan_mfma<<<R_ROWS / 32, 256, 0, stream>>>(
        qs, qd, w1h, w1l, freq_b, w2t, out_b, ident, n);
    float* t = qs; qs = qd; qd = t;
  }

  // k3: out = (q*v)@proj_W + proj_b  (qs == q_a)
  gemm_proj_mfma<<<dim3(128, 8), 256, 0, stream>>>(qs, v_bf, pWt, proj_b, out);
}

// Round 3
// 1046.773 us; speedup vs baseline: 4.7687x; 2.1855x over previous
//
#include <hip/hip_runtime.h>
#include <hip/hip_bf16.h>
#include <math.h>

// SSMBlock: B=8, T=2048, C=1024, NF=64. R = 16384 rows.
// Round 3: bf16 end-to-end + global_load_lds(16B) staging + xor-swizzled LDS
//          + LDS-staged coalesced epilogues.
// ws: Xb 32MB | Qb 32MB | Vb 32MB | aWt 4MB | pWt 2MB | w1t/w2t 0.5MB | identb
//     (~102.5MB).  Second scan buffer lives inside d_out (64MB fp32 space).

#define R_ROWS 16384
#define T_DIM  2048
#define C_DIM  1024

typedef unsigned short u16;
typedef __attribute__((ext_vector_type(8))) short short8;
typedef __attribute__((ext_vector_type(4))) float f32x4;

__device__ __forceinline__ u16 f2bf(float f) {
  union { float f; unsigned u; } v; v.f = f;
  unsigned r = v.u + 0x7fffu + ((v.u >> 16) & 1u);
  return (u16)(r >> 16);
}
__device__ __forceinline__ float bf2f(u16 h) {
  union { unsigned u; float f; } v; v.u = ((unsigned)h) << 16;
  return v.f;
}
// async 16B/lane global->LDS; LDS dest = uniform base + lane*16
__device__ __forceinline__ void gld16(const void* g, void* l) {
  __builtin_amdgcn_global_load_lds(
      (const __attribute__((address_space(1))) void*)g,
      (__attribute__((address_space(3))) void*)l, 16, 0, 0);
}

// ---------------- elementwise converts / product (8 elems/thread) ----------
__global__ __launch_bounds__(256) void cvt_bf16(const float* __restrict__ in,
                                                u16* __restrict__ out, int n8) {
  const int i = blockIdx.x * 256 + threadIdx.x;
  if (i >= n8) return;
  const float4 a = ((const float4*)in)[2 * i];
  const float4 b = ((const float4*)in)[2 * i + 1];
  alignas(16) u16 t[8] = {f2bf(a.x), f2bf(a.y), f2bf(a.z), f2bf(a.w),
                          f2bf(b.x), f2bf(b.y), f2bf(b.z), f2bf(b.w)};
  ((uint4*)out)[i] = *(const uint4*)t;
}

__global__ __launch_bounds__(256) void prod_bf16(const u16* __restrict__ a,
                                                 const u16* __restrict__ b,
                                                 u16* __restrict__ o, int n8) {
  const int i = blockIdx.x * 256 + threadIdx.x;
  if (i >= n8) return;
  uint4 ua = ((const uint4*)a)[i], ub = ((const uint4*)b)[i];
  const u16* pa = (const u16*)&ua;
  const u16* pb = (const u16*)&ub;
  alignas(16) u16 t[8];
#pragma unroll
  for (int c = 0; c < 8; c++) t[c] = f2bf(bf2f(pa[c]) * bf2f(pb[c]));
  ((uint4*)o)[i] = *(const uint4*)t;
}

// ---------------- weight transpose/convert: Wt[n][k] = bf16(W[k][n]) -------
__global__ __launch_bounds__(256) void cvt_T(const float* __restrict__ W,
                                             u16* __restrict__ Wt, int K, int N) {
  __shared__ float t[32][33];
  const int k0 = blockIdx.x * 32, n0 = blockIdx.y * 32;
  const int tx = threadIdx.x & 31, ty = threadIdx.x >> 5;
#pragma unroll
  for (int i = 0; i < 32; i += 8)
    t[ty + i][tx] = W[(size_t)(k0 + ty + i) * N + n0 + tx];
  __syncthreads();
#pragma unroll
  for (int i = 0; i < 32; i += 8)
    Wt[(size_t)(n0 + ty + i) * K + k0 + tx] = f2bf(t[tx][ty + i]);
}

// ---------------- GEMM bodies ----------------------------------------------
// A [M][1024] bf16, Bt [N][1024] bf16. 128x128 tile, BK=64, 4 waves 2x2.
// LDS physical segment = seg ^ (row&7)  (seg = 16B unit within a 64-col row).
// Staging is lane-linear (global_load_lds); swizzle applied on global col.

#define GEMM_KLOOP(Aptr, Bptr)                                                 \
  const int tid = threadIdx.x, lane = tid & 63, w = tid >> 6;                  \
  const int ln = lane & 15, qd = lane >> 4;                                    \
  const int wm = w & 1, wn = w >> 1;                                           \
  const int n0 = blockIdx.x * 128, m0 = blockIdx.y * 128;                      \
  const int srow = w * 32 + (lane >> 3);                                       \
  const int sl = (lane & 7) ^ ((lane >> 3) & 7); /* swizzled global seg */     \
  const int scol = sl * 8;                                                     \
  f32x4 acc[4][4] = {};                                                        \
  for (int kt = 0; kt < 1024; kt += 64) {                                      \
    __syncthreads();                                                           \
    _Pragma("unroll") for (int j = 0; j < 4; j++) {                            \
      gld16(&Aptr[(size_t)(m0 + srow + j * 8) * 1024 + kt + scol],             \
            &As[(w * 32 + j * 8) * 64]);                                       \
      gld16(&Bptr[(size_t)(n0 + srow + j * 8) * 1024 + kt + scol],             \
            &Bs[(w * 32 + j * 8) * 64]);                                       \
    }                                                                          \
    __syncthreads();                                                           \
    _Pragma("unroll") for (int ks = 0; ks < 2; ks++) {                         \
      short8 af[4], bf_[4];                                                    \
      _Pragma("unroll") for (int i = 0; i < 4; i++) {                          \
        const int ar = wm * 64 + i * 16 + ln;                                  \
        af[i] = *(const short8*)&As[ar * 64 + ((ks * 4 + qd) ^ (ar & 7)) * 8]; \
      }                                                                        \
      _Pragma("unroll") for (int j = 0; j < 4; j++) {                          \
        const int br = wn * 64 + j * 16 + ln;                                  \
        bf_[j] = *(const short8*)&Bs[br * 64 + ((ks * 4 + qd) ^ (br & 7)) * 8];\
      }                                                                        \
      _Pragma("unroll") for (int i = 0; i < 4; i++)                            \
      _Pragma("unroll") for (int j = 0; j < 4; j++)                            \
        acc[i][j] = __builtin_amdgcn_mfma_f32_16x16x32_bf16(af[i], bf_[j],     \
                                                            acc[i][j], 0, 0, 0);\
    }                                                                          \
  }                                                                            \
  __syncthreads();

// qv: M=16384 N=2048 K=1024; cols<1024 -> Qb, else -> Vb (both bf16).
__global__ __launch_bounds__(256) void gemm_qv_mfma(
    const u16* __restrict__ A, const u16* __restrict__ Bt,
    const float* __restrict__ bias, u16* __restrict__ Qb, u16* __restrict__ Vb) {
  __shared__ u16 S[16384];
  u16* As = S;
  u16* Bs = S + 8192;
  GEMM_KLOOP(A, Bt)
  // epilogue: bf16 tile in LDS (reuse S as Cs[128][128]) then coalesced store
#pragma unroll
  for (int j = 0; j < 4; j++) {
    const int col = wn * 64 + j * 16 + ln;
    const float bv = bias[n0 + col];
#pragma unroll
    for (int i = 0; i < 4; i++)
#pragma unroll
      for (int r = 0; r < 4; r++)
        S[(wm * 64 + i * 16 + qd * 4 + r) * 128 + col] = f2bf(acc[i][j][r] + bv);
  }
  __syncthreads();
  const bool isQ = (n0 < 1024);
  u16* dst = isQ ? Qb : Vb;
  const int nb = isQ ? n0 : n0 - 1024;
#pragma unroll
  for (int it = 0; it < 8; it++) {
    const int idx = it * 256 + tid;
    const int row = idx >> 4, seg = idx & 15;
    *(uint4*)&dst[(size_t)(m0 + row) * 1024 + nb + seg * 8] = ((const uint4*)S)[idx];
  }
}

// proj: M=16384 N=1024 K=1024; fp32 out (final), 2-pass LDS-staged epilogue.
__global__ __launch_bounds__(256) void gemm_proj_mfma(
    const u16* __restrict__ A, const u16* __restrict__ Bt,
    const float* __restrict__ bias, float* __restrict__ OUT) {
  __shared__ u16 S[16384];
  u16* As = S;
  u16* Bs = S + 8192;
  GEMM_KLOOP(A, Bt)
  float* Csf = (float*)S;  // 64 x 128 f32 = 32KB per pass
#pragma unroll
  for (int p = 0; p < 2; p++) {
    if (wm == p) {
#pragma unroll
      for (int j = 0; j < 4; j++) {
        const int col = wn * 64 + j * 16 + ln;
        const float bv = bias[n0 + col];
#pragma unroll
        for (int i = 0; i < 4; i++)
#pragma unroll
          for (int r = 0; r < 4; r++)
            Csf[(i * 16 + qd * 4 + r) * 128 + col] = acc[i][j][r] + bv;
      }
    }
    __syncthreads();
#pragma unroll
    for (int it = 0; it < 8; it++) {
      const int idx = it * 256 + tid;
      const int row = idx >> 5, seg = idx & 31;
      *(uint4*)&OUT[(size_t)(m0 + p * 64 + row) * 1024 + n0 + seg * 4] =
          ((const uint4*)Csf)[idx];
    }
    __syncthreads();
  }
}

// ---------------- scan step -------------------------------------------------
// 32 rows/block, 512 blocks. src/dst bf16 [16384][1024].
// Phase1: f[32][64] = z[32][2048]@W1t  (z staged via gld16, swizzled).
// sincos -> St bf16. Phase2: z2[32][1024] = St@W2t (B from L2). mmnorm.
// Epilogue: 2 halves of 16 rows staged in LDS -> coalesced uint4 stores.
__global__ __launch_bounds__(256) void scan_mfma(
    const u16* __restrict__ src, u16* __restrict__ dst,
    const u16* __restrict__ W1t, const float* __restrict__ b1,
    const u16* __restrict__ W2t, const float* __restrict__ b2,
    const u16* __restrict__ identb, int n) {
  __shared__ u16 U[16384];          // Zs = U[0..8191], St = U[8192..12287]
  __shared__ unsigned rmax[32];     // Outs (16x1024) = U[0..16383]
  u16* Zs = U;
  u16* St = U + 8192;
  const int tid = threadIdx.x, lane = tid & 63, w = tid >> 6;
  const int ln = lane & 15, qd = lane >> 4;
  const int r0 = blockIdx.x * 32;
  const int mt = w & 1, nb = w >> 1;
  const int zrow = w * 8 + (lane >> 5);   // + j*2
  const int zs = lane & 31;               // physical 16B slot in row
  f32x4 fa[2] = {};

  for (int kc = 0; kc < 2048; kc += 256) {
    __syncthreads();
#pragma unroll
    for (int j = 0; j < 4; j++) {
      const int row = zrow + j * 2;
      const int gr = r0 + row;
      const int tl = gr & (T_DIM - 1);
      const int l = zs ^ (row & 7);       // logical seg (xor low3)
      const u16* base;
      if (kc < 1024)
        base = (tl >= n) ? src + (size_t)(gr - n) * 1024 + kc : identb + kc;
      else
        base = src + (size_t)gr * 1024 + (kc - 1024);
      gld16(base + l * 8, &Zs[(w * 8 + j * 2) * 256]);
    }
    __syncthreads();
#pragma unroll
    for (int ks = 0; ks < 8; ks++) {
      const int ar = mt * 16 + ln;
      const short8 ah =
          *(const short8*)&Zs[ar * 256 + ((ks * 4 + qd) ^ (ar & 7)) * 8];
#pragma unroll
      for (int t2 = 0; t2 < 2; t2++) {
        const int cn = (nb + 2 * t2) * 16 + ln;
        const short8 bh = *(const short8*)&W1t[(size_t)cn * 2048 + kc + ks * 32 + qd * 8];
        fa[t2] = __builtin_amdgcn_mfma_f32_16x16x32_bf16(ah, bh, fa[t2], 0, 0, 0);
      }
    }
  }
  // sincos -> St (swizzled rows)
  if (tid < 32) rmax[tid] = 0u;
#pragma unroll
  for (int t2 = 0; t2 < 2; t2++) {
    const int cn = (nb + 2 * t2) * 16 + ln;
    const float b1v = b1[cn];
#pragma unroll
    for (int r = 0; r < 4; r++) {
      const float f = fa[t2][r] + b1v;
      float sv, cv;
      __sincosf(f, &sv, &cv);
      const int row = mt * 16 + qd * 4 + r;
      const int rx = row & 7;
      St[row * 128 + ((cn >> 3) ^ rx) * 8 + (cn & 7)] = f2bf(sv);
      St[row * 128 + (((cn + 64) >> 3) ^ rx) * 8 + (cn & 7)] = f2bf(cv);
    }
  }
  __syncthreads();
  // prefetch phase-2 A-frags (frees St for epilogue reuse)
  short8 pa[2][4];
#pragma unroll
  for (int m = 0; m < 2; m++)
#pragma unroll
    for (int ks = 0; ks < 4; ks++) {
      const int ar = m * 16 + ln;
      pa[m][ks] = *(const short8*)&St[ar * 128 + ((ks * 4 + qd) ^ (ar & 7)) * 8];
    }
  // phase 2: wave w covers cols [w*256, w*256+256)
  f32x4 a2[2][16] = {};
#pragma unroll
  for (int nt = 0; nt < 16; nt++) {
    const int cn = w * 256 + nt * 16 + ln;
#pragma unroll
    for (int ks = 0; ks < 4; ks++) {
      const short8 b = *(const short8*)&W2t[(size_t)cn * 128 + ks * 32 + qd * 8];
      a2[0][nt] = __builtin_amdgcn_mfma_f32_16x16x32_bf16(pa[0][ks], b, a2[0][nt], 0, 0, 0);
      a2[1][nt] = __builtin_amdgcn_mfma_f32_16x16x32_bf16(pa[1][ks], b, a2[1][nt], 0, 0, 0);
    }
  }
  // bias + per-row absmax
  float mx[2][4] = {{0.f, 0.f, 0.f, 0.f}, {0.f, 0.f, 0.f, 0.f}};
#pragma unroll
  for (int nt = 0; nt < 16; nt++) {
    const float bv = b2[w * 256 + nt * 16 + ln];
#pragma unroll
    for (int m = 0; m < 2; m++)
#pragma unroll
      for (int r = 0; r < 4; r++) {
        const float v = a2[m][nt][r] + bv;
        a2[m][nt][r] = v;
        mx[m][r] = fmaxf(mx[m][r], fabsf(v));
      }
  }
#pragma unroll
  for (int m = 0; m < 2; m++)
#pragma unroll
    for (int r = 0; r < 4; r++) {
      float v = mx[m][r];
      v = fmaxf(v, __shfl_xor(v, 1, 64));
      v = fmaxf(v, __shfl_xor(v, 2, 64));
      v = fmaxf(v, __shfl_xor(v, 4, 64));
      v = fmaxf(v, __shfl_xor(v, 8, 64));
      if (ln == 0) atomicMax(&rmax[m * 16 + qd * 4 + r], __float_as_uint(v));
    }
  __syncthreads();
  // normalize + write via LDS (Outs = U, 16 rows x 1024 cols per half)
#pragma unroll
  for (int h = 0; h < 2; h++) {
    float inv[4];
#pragma unroll
    for (int r = 0; r < 4; r++)
      inv[r] = 1.0f / (__uint_as_float(rmax[h * 16 + qd * 4 + r]) + 1e-6f);
#pragma unroll
    for (int nt = 0; nt < 16; nt++) {
      const int cn = w * 256 + nt * 16 + ln;
#pragma unroll
      for (int r = 0; r < 4; r++)
        U[(qd * 4 + r) * 1024 + cn] = f2bf(a2[h][nt][r] * inv[r]);
    }
    __syncthreads();
#pragma unroll
    for (int it = 0; it < 8; it++) {
      const int idx = it * 256 + tid;
      const int row = idx >> 7, seg = idx & 127;
      *(uint4*)&dst[(size_t)(r0 + h * 16 + row) * 1024 + seg * 8] =
          ((const uint4*)U)[idx];
    }
    __syncthreads();
  }
}

// ---------------- launch ----------------------------------------------------
extern "C" void kernel_launch(void* const* d_in, const int* in_sizes, int n_in,
                              void* d_out, int out_size, void* d_ws, size_t ws_size,
                              hipStream_t stream) {
  const float* x      = (const float*)d_in[0];
  const float* attn_W = (const float*)d_in[1];
  const float* attn_b = (const float*)d_in[2];
  const float* freq_W = (const float*)d_in[3];
  const float* freq_b = (const float*)d_in[4];
  const float* out_W  = (const float*)d_in[5];
  const float* out_b  = (const float*)d_in[6];
  const float* proj_W = (const float*)d_in[7];
  const float* proj_b = (const float*)d_in[8];
  const float* ident  = (const float*)d_in[9];
  float* out = (float*)d_out;

  const size_t RC = (size_t)R_ROWS * C_DIM;
  u16* Xb     = (u16*)d_ws;              // 32MB (later reused as prod output)
  u16* Qb     = Xb + RC;                 // 32MB scan buf A
  u16* Vb     = Qb + RC;                 // 32MB
  u16* aWt    = Vb + RC;                 // 2048*1024
  u16* pWt    = aWt + (size_t)2048 * 1024;
  u16* w1t    = pWt + (size_t)1024 * 1024;   // 64*2048
  u16* w2t    = w1t + (size_t)64 * 2048;     // 1024*128
  u16* identb = w2t + (size_t)1024 * 128;    // 1024
  u16* Qc     = (u16*)d_out;             // scan buf B inside d_out (32MB of 64MB)

  // prep
  cvt_bf16<<<8192, 256, 0, stream>>>(x, Xb, (int)(RC / 8));
  cvt_bf16<<<1, 256, 0, stream>>>(ident, identb, 128);
  cvt_T<<<dim3(32, 64), 256, 0, stream>>>(attn_W, aWt, 1024, 2048);
  cvt_T<<<dim3(32, 32), 256, 0, stream>>>(proj_W, pWt, 1024, 1024);
  cvt_T<<<dim3(4, 32), 256, 0, stream>>>(out_W, w2t, 128, 1024);
  cvt_T<<<dim3(64, 2), 256, 0, stream>>>(freq_W, w1t, 2048, 64);

  // k1: qv
  gemm_qv_mfma<<<dim3(16, 128), 256, 0, stream>>>(Xb, aWt, attn_b, Qb, Vb);

  // 11 scan steps: Qb -> Qc -> Qb ... (11 odd => final in Qc)
  u16* qs = Qb;
  u16* qd = Qc;
  for (int n = 1; n < T_DIM; n <<= 1) {
    scan_mfma<<<512, 256, 0, stream>>>(qs, qd, w1t, freq_b, w2t, out_b, identb, n);
    u16* t = qs; qs = qd; qd = t;
  }

  // prod: (q*v) -> Xb (dead), then proj -> d_out (fp32)
  prod_bf16<<<8192, 256, 0, stream>>>(qs, Vb, Xb, (int)(RC / 8));
  gemm_proj_mfma<<<dim3(8, 128), 256, 0, stream>>>(Xb, pWt, proj_b, out);
}

// Round 4
// 919.447 us; speedup vs baseline: 5.4291x; 1.1385x over previous
//
#include <hip/hip_runtime.h>
#include <hip/hip_bf16.h>
#include <math.h>

// SSMBlock: B=8, T=2048, C=1024, NF=64. R = 16384 rows.
// Round 4: scan restructured. Per step k: G_k = q_k @ [W1_top|W1_bot] is the
// only state (16384x128 f32). One fused kernel per step:
//   f = G1_prev[gr-n] (or fid) + G2_prev[gr] + b1 ; S=[sin f,cos f] ->
//   z2 = S@W2 + b2 ; mmnorm (block covers full row) -> q-tile (LDS bf16) ->
//   G_next = q_tile @ W1full  (fused; skipped on last step, which writes q).
// ws: Xb 32M | Qb 32M | Vb 32M | aWt 4M | pWt 2M | w2t/.w1f 512K | Ga/Gb 16M | fid

#define R_ROWS 16384
#define T_DIM  2048
#define C_DIM  1024

typedef unsigned short u16;
typedef __attribute__((ext_vector_type(8))) short short8;
typedef __attribute__((ext_vector_type(4))) float f32x4;

__device__ __forceinline__ u16 f2bf(float f) {
  union { float f; unsigned u; } v; v.f = f;
  unsigned r = v.u + 0x7fffu + ((v.u >> 16) & 1u);
  return (u16)(r >> 16);
}
__device__ __forceinline__ float bf2f(u16 h) {
  union { unsigned u; float f; } v; v.u = ((unsigned)h) << 16;
  return v.f;
}
__device__ __forceinline__ void gld16(const void* g, void* l) {
  __builtin_amdgcn_global_load_lds(
      (const __attribute__((address_space(1))) void*)g,
      (__attribute__((address_space(3))) void*)l, 16, 0, 0);
}

// ---------------- elementwise ----------------------------------------------
__global__ __launch_bounds__(256) void cvt_bf16(const float* __restrict__ in,
                                                u16* __restrict__ out, int n8) {
  const int i = blockIdx.x * 256 + threadIdx.x;
  if (i >= n8) return;
  const float4 a = ((const float4*)in)[2 * i];
  const float4 b = ((const float4*)in)[2 * i + 1];
  alignas(16) u16 t[8] = {f2bf(a.x), f2bf(a.y), f2bf(a.z), f2bf(a.w),
                          f2bf(b.x), f2bf(b.y), f2bf(b.z), f2bf(b.w)};
  ((uint4*)out)[i] = *(const uint4*)t;
}

__global__ __launch_bounds__(256) void prod_bf16(const u16* __restrict__ a,
                                                 const u16* __restrict__ b,
                                                 u16* __restrict__ o, int n8) {
  const int i = blockIdx.x * 256 + threadIdx.x;
  if (i >= n8) return;
  uint4 ua = ((const uint4*)a)[i], ub = ((const uint4*)b)[i];
  const u16* pa = (const u16*)&ua;
  const u16* pb = (const u16*)&ub;
  alignas(16) u16 t[8];
#pragma unroll
  for (int c = 0; c < 8; c++) t[c] = f2bf(bf2f(pa[c]) * bf2f(pb[c]));
  ((uint4*)o)[i] = *(const uint4*)t;
}

// ---------------- weight prep ----------------------------------------------
__global__ __launch_bounds__(256) void cvt_T(const float* __restrict__ W,
                                             u16* __restrict__ Wt, int K, int N) {
  __shared__ float t[32][33];
  const int k0 = blockIdx.x * 32, n0 = blockIdx.y * 32;
  const int tx = threadIdx.x & 31, ty = threadIdx.x >> 5;
#pragma unroll
  for (int i = 0; i < 32; i += 8)
    t[ty + i][tx] = W[(size_t)(k0 + ty + i) * N + n0 + tx];
  __syncthreads();
#pragma unroll
  for (int i = 0; i < 32; i += 8)
    Wt[(size_t)(n0 + ty + i) * K + k0 + tx] = f2bf(t[tx][ty + i]);
}

// freq_W [2048][64] -> W1f [128][1024]: rows 0..63 = top (k<1024), 64..127 = bot
__global__ __launch_bounds__(256) void cvt_w1f(const float* __restrict__ W,
                                               u16* __restrict__ W1f) {
  __shared__ float t[32][33];
  const int k0 = blockIdx.x * 32, n0 = blockIdx.y * 32;
  const int tx = threadIdx.x & 31, ty = threadIdx.x >> 5;
#pragma unroll
  for (int i = 0; i < 32; i += 8)
    t[ty + i][tx] = W[(size_t)(k0 + ty + i) * 64 + n0 + tx];
  __syncthreads();
#pragma unroll
  for (int i = 0; i < 32; i += 8) {
    const int k = k0 + tx;
    const int row = (n0 + ty + i) + ((k >= 1024) ? 64 : 0);
    W1f[(size_t)row * 1024 + (k & 1023)] = f2bf(t[tx][ty + i]);
  }
}

// fid[j] = sum_{k<1024} identity[k] * freq_W[k][j]
__global__ __launch_bounds__(256) void fid_kernel(const float* __restrict__ ident,
                                                  const float* __restrict__ W,
                                                  float* __restrict__ fid) {
  __shared__ float red[256];
  const int tid = threadIdx.x;
  const int j = tid >> 2, part = tid & 3;
  float s = 0.f;
  for (int k = part * 256; k < part * 256 + 256; k++)
    s += ident[k] * W[(size_t)k * 64 + j];
  red[tid] = s;
  __syncthreads();
  if (part == 0) fid[j] = red[tid] + red[tid + 1] + red[tid + 2] + red[tid + 3];
}

// ---------------- big GEMMs (m97-style, from R3) ----------------------------
#define GEMM_KLOOP(Aptr, Bptr)                                                 \
  const int tid = threadIdx.x, lane = tid & 63, w = tid >> 6;                  \
  const int ln = lane & 15, qd = lane >> 4;                                    \
  const int wm = w & 1, wn = w >> 1;                                           \
  const int n0 = blockIdx.x * 128, m0 = blockIdx.y * 128;                      \
  const int srow = w * 32 + (lane >> 3);                                       \
  const int sl = (lane & 7) ^ ((lane >> 3) & 7);                               \
  const int scol = sl * 8;                                                     \
  f32x4 acc[4][4] = {};                                                        \
  for (int kt = 0; kt < 1024; kt += 64) {                                      \
    __syncthreads();                                                           \
    _Pragma("unroll") for (int j = 0; j < 4; j++) {                            \
      gld16(&Aptr[(size_t)(m0 + srow + j * 8) * 1024 + kt + scol],             \
            &As[(w * 32 + j * 8) * 64]);                                       \
      gld16(&Bptr[(size_t)(n0 + srow + j * 8) * 1024 + kt + scol],             \
            &Bs[(w * 32 + j * 8) * 64]);                                       \
    }                                                                          \
    __syncthreads();                                                           \
    _Pragma("unroll") for (int ks = 0; ks < 2; ks++) {                         \
      short8 af[4], bf_[4];                                                    \
      _Pragma("unroll") for (int i = 0; i < 4; i++) {                          \
        const int ar = wm * 64 + i * 16 + ln;                                  \
        af[i] = *(const short8*)&As[ar * 64 + ((ks * 4 + qd) ^ (ar & 7)) * 8]; \
      }                                                                        \
      _Pragma("unroll") for (int j = 0; j < 4; j++) {                          \
        const int br = wn * 64 + j * 16 + ln;                                  \
        bf_[j] = *(const short8*)&Bs[br * 64 + ((ks * 4 + qd) ^ (br & 7)) * 8];\
      }                                                                        \
      _Pragma("unroll") for (int i = 0; i < 4; i++)                            \
      _Pragma("unroll") for (int j = 0; j < 4; j++)                            \
        acc[i][j] = __builtin_amdgcn_mfma_f32_16x16x32_bf16(af[i], bf_[j],     \
                                                            acc[i][j], 0, 0, 0);\
    }                                                                          \
  }                                                                            \
  __syncthreads();

__global__ __launch_bounds__(256) void gemm_qv_mfma(
    const u16* __restrict__ A, const u16* __restrict__ Bt,
    const float* __restrict__ bias, u16* __restrict__ Qb, u16* __restrict__ Vb) {
  __shared__ u16 S[16384];
  u16* As = S;
  u16* Bs = S + 8192;
  GEMM_KLOOP(A, Bt)
#pragma unroll
  for (int j = 0; j < 4; j++) {
    const int col = wn * 64 + j * 16 + ln;
    const float bv = bias[n0 + col];
#pragma unroll
    for (int i = 0; i < 4; i++)
#pragma unroll
      for (int r = 0; r < 4; r++)
        S[(wm * 64 + i * 16 + qd * 4 + r) * 128 + col] = f2bf(acc[i][j][r] + bv);
  }
  __syncthreads();
  const bool isQ = (n0 < 1024);
  u16* dst = isQ ? Qb : Vb;
  const int nb = isQ ? n0 : n0 - 1024;
#pragma unroll
  for (int it = 0; it < 8; it++) {
    const int idx = it * 256 + tid;
    const int row = idx >> 4, seg = idx & 15;
    *(uint4*)&dst[(size_t)(m0 + row) * 1024 + nb + seg * 8] = ((const uint4*)S)[idx];
  }
}

__global__ __launch_bounds__(256) void gemm_proj_mfma(
    const u16* __restrict__ A, const u16* __restrict__ Bt,
    const float* __restrict__ bias, float* __restrict__ OUT) {
  __shared__ u16 S[16384];
  u16* As = S;
  u16* Bs = S + 8192;
  GEMM_KLOOP(A, Bt)
  float* Csf = (float*)S;
#pragma unroll
  for (int p = 0; p < 2; p++) {
    if (wm == p) {
#pragma unroll
      for (int j = 0; j < 4; j++) {
        const int col = wn * 64 + j * 16 + ln;
        const float bv = bias[n0 + col];
#pragma unroll
        for (int i = 0; i < 4; i++)
#pragma unroll
          for (int r = 0; r < 4; r++)
            Csf[(i * 16 + qd * 4 + r) * 128 + col] = acc[i][j][r] + bv;
      }
    }
    __syncthreads();
#pragma unroll
    for (int it = 0; it < 8; it++) {
      const int idx = it * 256 + tid;
      const int row = idx >> 5, seg = idx & 31;
      *(uint4*)&OUT[(size_t)(m0 + p * 64 + row) * 1024 + n0 + seg * 4] =
          ((const uint4*)Csf)[idx];
    }
    __syncthreads();
  }
}

// ---------------- G0 = q @ W1full : M=16384 N=128 K=1024 --------------------
// 256 threads (4 waves 2m x 2n), m-tile 64, grid 256.
__global__ __launch_bounds__(256) void g0_kernel(const u16* __restrict__ Qb,
                                                 const u16* __restrict__ W1f,
                                                 float* __restrict__ G) {
  __shared__ u16 As[64 * 64];  // 8KB
  const int tid = threadIdx.x, lane = tid & 63, wv = tid >> 6;
  const int ln = lane & 15, qd = lane >> 4;
  const int wm = wv >> 1, wn = wv & 1;
  const int m0 = blockIdx.x * 64;
  const int srow = wv * 16 + (lane >> 3);
  const int scol = ((lane & 7) ^ ((lane >> 3) & 7)) * 8;
  f32x4 acc[2][4] = {};
  for (int kt = 0; kt < 1024; kt += 64) {
    __syncthreads();
#pragma unroll
    for (int j = 0; j < 2; j++)
      gld16(&Qb[(size_t)(m0 + srow + j * 8) * 1024 + kt + scol],
            &As[(wv * 16 + j * 8) * 64]);
    __syncthreads();
#pragma unroll
    for (int ks = 0; ks < 2; ks++) {
      short8 a[2];
#pragma unroll
      for (int i = 0; i < 2; i++) {
        const int ar = wm * 32 + i * 16 + ln;
        a[i] = *(const short8*)&As[ar * 64 + ((ks * 4 + qd) ^ (ar & 7)) * 8];
      }
#pragma unroll
      for (int nt = 0; nt < 4; nt++) {
        const short8 b = *(const short8*)&W1f[(size_t)(wn * 64 + nt * 16 + ln) * 1024 +
                                              kt + ks * 32 + qd * 8];
#pragma unroll
        for (int i = 0; i < 2; i++)
          acc[i][nt] = __builtin_amdgcn_mfma_f32_16x16x32_bf16(a[i], b, acc[i][nt], 0, 0, 0);
      }
    }
  }
#pragma unroll
  for (int i = 0; i < 2; i++)
#pragma unroll
    for (int nt = 0; nt < 4; nt++)
#pragma unroll
      for (int r = 0; r < 4; r++)
        G[(size_t)(m0 + wm * 32 + i * 16 + qd * 4 + r) * 128 + wn * 64 + nt * 16 + ln] =
            acc[i][nt][r];
}

// ---------------- fused scan step -------------------------------------------
// 512 threads (8 waves: 2 wm x 4 wn), 64 rows/block, grid 256.
// flags: 1 = write q to Qout (last step), 2 = compute Gdst (all but last).
__global__ __launch_bounds__(512) void scan_fused(
    const float* __restrict__ Gsrc, float* __restrict__ Gdst,
    const u16* __restrict__ W1f, const u16* __restrict__ W2t,
    const float* __restrict__ b1, const float* __restrict__ b2,
    const float* __restrict__ fid, u16* __restrict__ Qout, int n, int flags) {
  __shared__ u16 Sa[64 * 128];    // 16KB  S (A-frags for P1)
  __shared__ u16 Os[16 * 1024];   // 32KB  q-tile pass buffer
  __shared__ unsigned rmax[64];
  const int tid = threadIdx.x, lane = tid & 63, wv = tid >> 6;
  const int ln = lane & 15, qd = lane >> 4;
  const int wm = wv >> 2, wn = wv & 3;
  const int r0 = blockIdx.x * 64;
  if (tid < 64) rmax[tid] = 0u;
  // ---- P0: f = G1[gr-n]|fid + G2[gr] + b1 ; sincos -> Sa (swizzled)
  {
    const int r = tid >> 3, js = (tid & 7) << 3;
    const int gr = r0 + r, tl = gr & (T_DIM - 1);
    const float* g1p = (tl >= n) ? &Gsrc[(size_t)(gr - n) * 128 + js] : &fid[js];
    const float4 g1a = ((const float4*)g1p)[0], g1b = ((const float4*)g1p)[1];
    const float* g2p = &Gsrc[(size_t)gr * 128 + 64 + js];
    const float4 g2a = ((const float4*)g2p)[0], g2b = ((const float4*)g2p)[1];
    const float4 ba = ((const float4*)&b1[js])[0], bb4 = ((const float4*)&b1[js])[1];
    float f[8] = {g1a.x + g2a.x + ba.x,  g1a.y + g2a.y + ba.y,
                  g1a.z + g2a.z + ba.z,  g1a.w + g2a.w + ba.w,
                  g1b.x + g2b.x + bb4.x, g1b.y + g2b.y + bb4.y,
                  g1b.z + g2b.z + bb4.z, g1b.w + g2b.w + bb4.w};
    alignas(16) u16 sn[8], cs[8];
#pragma unroll
    for (int c = 0; c < 8; c++) {
      float sv, cv;
      __sincosf(f[c], &sv, &cv);
      sn[c] = f2bf(sv);
      cs[c] = f2bf(cv);
    }
    const int ph = (js >> 3) ^ (r & 7);
    *(uint4*)&Sa[r * 128 + ph * 8] = *(const uint4*)sn;
    *(uint4*)&Sa[r * 128 + (ph + 8) * 8] = *(const uint4*)cs;
  }
  __syncthreads();
  // ---- P1: z2 = S @ W2t + b2 ; per-row absmax
  short8 af[2][4];
#pragma unroll
  for (int i = 0; i < 2; i++) {
    const int ar = wm * 32 + i * 16 + ln;
#pragma unroll
    for (int ks = 0; ks < 4; ks++)
      af[i][ks] = *(const short8*)&Sa[ar * 128 +
                                      ((((ks << 2) + qd) & 8) |
                                       ((((ks << 2) + qd) ^ ar) & 7)) * 8];
  }
  f32x4 acc[2][16] = {};
#pragma unroll
  for (int nt = 0; nt < 16; nt++) {
    const int cn = wn * 256 + nt * 16 + ln;
#pragma unroll
    for (int ks = 0; ks < 4; ks++) {
      const short8 b = *(const short8*)&W2t[(size_t)cn * 128 + ks * 32 + qd * 8];
      acc[0][nt] = __builtin_amdgcn_mfma_f32_16x16x32_bf16(af[0][ks], b, acc[0][nt], 0, 0, 0);
      acc[1][nt] = __builtin_amdgcn_mfma_f32_16x16x32_bf16(af[1][ks], b, acc[1][nt], 0, 0, 0);
    }
  }
  float mx[2][4] = {{0.f, 0.f, 0.f, 0.f}, {0.f, 0.f, 0.f, 0.f}};
#pragma unroll
  for (int nt = 0; nt < 16; nt++) {
    const float bv = b2[wn * 256 + nt * 16 + ln];
#pragma unroll
    for (int i = 0; i < 2; i++)
#pragma unroll
      for (int r = 0; r < 4; r++) {
        const float v = acc[i][nt][r] + bv;
        acc[i][nt][r] = v;
        mx[i][r] = fmaxf(mx[i][r], fabsf(v));
      }
  }
#pragma unroll
  for (int i = 0; i < 2; i++)
#pragma unroll
    for (int r = 0; r < 4; r++) {
      float v = mx[i][r];
      v = fmaxf(v, __shfl_xor(v, 1, 64));
      v = fmaxf(v, __shfl_xor(v, 2, 64));
      v = fmaxf(v, __shfl_xor(v, 4, 64));
      v = fmaxf(v, __shfl_xor(v, 8, 64));
      if (ln == 0) atomicMax(&rmax[wm * 32 + i * 16 + qd * 4 + r], __float_as_uint(v));
    }
  __syncthreads();
  float inv[2][4];
#pragma unroll
  for (int i = 0; i < 2; i++)
#pragma unroll
    for (int r = 0; r < 4; r++)
      inv[i][r] = 1.0f / (__uint_as_float(rmax[wm * 32 + i * 16 + qd * 4 + r]) + 1e-6f);
  // ---- P2: 4 passes of 16 rows: normalize -> Os; then Qout copy / G' chunk
  const int gc = wv * 16 + ln;  // G' column owned by this wave
#pragma unroll
  for (int p = 0; p < 4; p++) {
    if (wm == (p >> 1)) {
      const int i = p & 1;
#pragma unroll
      for (int nt = 0; nt < 16; nt++) {
        const int cn = wn * 256 + nt * 16 + ln;
#pragma unroll
        for (int r = 0; r < 4; r++) {
          const int lrow = qd * 4 + r;
          const int s = cn >> 3;
          const int phys = (s & ~7) | ((s ^ lrow) & 7);
          Os[lrow * 1024 + phys * 8 + (cn & 7)] = f2bf(acc[i][nt][r] * inv[i][r]);
        }
      }
    }
    __syncthreads();
    if (flags & 1) {  // write q rows r0+p*16 .. +15
#pragma unroll
      for (int it = 0; it < 4; it++) {
        const int idx = it * 512 + tid;
        const int lrow = idx >> 7, s = idx & 127;
        const int phys = (s & ~7) | ((s ^ lrow) & 7);
        *(uint4*)&Qout[(size_t)(r0 + p * 16 + lrow) * 1024 + s * 8] =
            *(const uint4*)&Os[lrow * 1024 + phys * 8];
      }
    }
    if (flags & 2) {  // G' chunk: rows p*16..+15, cols gc
      f32x4 g0 = {}, g1 = {};
#pragma unroll
      for (int ks = 0; ks < 32; ks += 2) {
        const int s0 = ks * 4 + qd, s1 = (ks + 1) * 4 + qd;
        const short8 a0 = *(const short8*)&Os[ln * 1024 +
                                              ((s0 & ~7) | ((s0 ^ ln) & 7)) * 8];
        const short8 a1 = *(const short8*)&Os[ln * 1024 +
                                              ((s1 & ~7) | ((s1 ^ ln) & 7)) * 8];
        const short8 b0 = *(const short8*)&W1f[(size_t)gc * 1024 + ks * 32 + qd * 8];
        const short8 b1v = *(const short8*)&W1f[(size_t)gc * 1024 + (ks + 1) * 32 + qd * 8];
        g0 = __builtin_amdgcn_mfma_f32_16x16x32_bf16(a0, b0, g0, 0, 0, 0);
        g1 = __builtin_amdgcn_mfma_f32_16x16x32_bf16(a1, b1v, g1, 0, 0, 0);
      }
#pragma unroll
      for (int r = 0; r < 4; r++)
        Gdst[(size_t)(r0 + p * 16 + qd * 4 + r) * 128 + gc] = g0[r] + g1[r];
    }
    __syncthreads();
  }
}

// ---------------- launch ----------------------------------------------------
extern "C" void kernel_launch(void* const* d_in, const int* in_sizes, int n_in,
                              void* d_out, int out_size, void* d_ws, size_t ws_size,
                              hipStream_t stream) {
  const float* x      = (const float*)d_in[0];
  const float* attn_W = (const float*)d_in[1];
  const float* attn_b = (const float*)d_in[2];
  const float* freq_W = (const float*)d_in[3];
  const float* freq_b = (const float*)d_in[4];
  const float* out_W  = (const float*)d_in[5];
  const float* out_b  = (const float*)d_in[6];
  const float* proj_W = (const float*)d_in[7];
  const float* proj_b = (const float*)d_in[8];
  const float* ident  = (const float*)d_in[9];
  float* out = (float*)d_out;

  const size_t RC = (size_t)R_ROWS * C_DIM;
  u16* Xb  = (u16*)d_ws;                     // 32MB
  u16* Qb  = Xb + RC;                        // 32MB
  u16* Vb  = Qb + RC;                        // 32MB
  u16* aWt = Vb + RC;                        // 4MB
  u16* pWt = aWt + (size_t)2048 * 1024;      // 2MB
  u16* w2t = pWt + (size_t)1024 * 1024;      // 256KB
  u16* w1f = w2t + (size_t)1024 * 128;       // 256KB
  float* Ga  = (float*)(w1f + (size_t)128 * 1024);  // 8MB
  float* Gb  = Ga + (size_t)R_ROWS * 128;           // 8MB
  float* fid = Gb + (size_t)R_ROWS * 128;           // 256B

  // prep
  cvt_bf16<<<8192, 256, 0, stream>>>(x, Xb, (int)(RC / 8));
  cvt_T<<<dim3(32, 64), 256, 0, stream>>>(attn_W, aWt, 1024, 2048);
  cvt_T<<<dim3(32, 32), 256, 0, stream>>>(proj_W, pWt, 1024, 1024);
  cvt_T<<<dim3(4, 32), 256, 0, stream>>>(out_W, w2t, 128, 1024);
  cvt_w1f<<<dim3(64, 2), 256, 0, stream>>>(freq_W, w1f);
  fid_kernel<<<1, 256, 0, stream>>>(ident, freq_W, fid);

  // q0, v
  gemm_qv_mfma<<<dim3(16, 128), 256, 0, stream>>>(Xb, aWt, attn_b, Qb, Vb);
  // G0 = q0 @ W1full
  g0_kernel<<<256, 256, 0, stream>>>(Qb, w1f, Ga);

  // 11 fused steps over G; last writes q into Qb (dead after g0)
  float* gs = Ga;
  float* gd = Gb;
  for (int n = 1; n < T_DIM; n <<= 1) {
    const int last = (n == 1024);
    scan_fused<<<256, 512, 0, stream>>>(gs, gd, w1f, w2t, freq_b, out_b, fid,
                                        Qb, n, last ? 1 : 2);
    float* t = gs; gs = gd; gd = t;
  }

  // Y = q*v ; out = Y @ proj_W + proj_b
  prod_bf16<<<8192, 256, 0, stream>>>(Qb, Vb, Xb, (int)(RC / 8));
  gemm_proj_mfma<<<dim3(8, 128), 256, 0, stream>>>(Xb, pWt, proj_b, out);
}